// Round 1
// baseline (1545.130 us; speedup 1.0000x reference)
//
#include <hip/hip_runtime.h>

#define NNODES 60000
#define NEDGES 960000
#define NGRAPH 10000

// ---------------- degree / CSR build ----------------

__global__ void count_deg_k(const int* __restrict__ ei, int* __restrict__ deg) {
  int e = blockIdx.x * blockDim.x + threadIdx.x;
  atomicAdd(&deg[ei[NEDGES + e]], 1);
}

__global__ void dinv_k(const int* __restrict__ deg, float* __restrict__ dinv) {
  int i = blockIdx.x * blockDim.x + threadIdx.x;
  if (i < NNODES) dinv[i] = rsqrtf((float)deg[i] + 1.0f);
}

__global__ void scan1_k(const int* __restrict__ deg, int* __restrict__ rs, int* __restrict__ bsum) {
  __shared__ int s[256];
  int tid = threadIdx.x;
  int i = blockIdx.x * 256 + tid;
  int v = (i < NNODES) ? deg[i] : 0;
  int x = v;
  s[tid] = x; __syncthreads();
  #pragma unroll
  for (int off = 1; off < 256; off <<= 1) {
    int t = (tid >= off) ? s[tid - off] : 0;
    __syncthreads();
    x += t; s[tid] = x; __syncthreads();
  }
  if (i < NNODES) rs[i] = x - v;              // exclusive within block
  if (tid == 255) bsum[blockIdx.x] = x;       // block total
}

__global__ void scan2_k(int* __restrict__ bsum, int nb) {
  __shared__ int s[256];
  int tid = threadIdx.x;
  int v = (tid < nb) ? bsum[tid] : 0;
  int x = v; s[tid] = x; __syncthreads();
  #pragma unroll
  for (int off = 1; off < 256; off <<= 1) {
    int t = (tid >= off) ? s[tid - off] : 0;
    __syncthreads();
    x += t; s[tid] = x; __syncthreads();
  }
  if (tid < nb) bsum[tid] = x - v;            // exclusive block offsets
}

__global__ void scan3_k(int* __restrict__ rs, const int* __restrict__ bsum) {
  int i = blockIdx.x * 256 + threadIdx.x;
  if (i < NNODES) rs[i] += bsum[blockIdx.x];
  if (i == 0) rs[NNODES] = NEDGES;
}

__global__ void scatter_k(const int* __restrict__ ei, const int* __restrict__ rs,
                          int* __restrict__ cursor, int* __restrict__ csr) {
  int e = blockIdx.x * blockDim.x + threadIdx.x;
  int s = ei[e], d = ei[NEDGES + e];
  int pos = rs[d] + atomicAdd(&cursor[d], 1);
  csr[pos] = s;
}

// ---------------- GEMM: Y[r] = (X @ W)[r] * dinv[r],  X:[M,256] W:[256,256] ----------------
// 128x128 tile, BK=16, 8x8 micro-tile per thread (rows ty*4+{0..3, 64..67}, cols likewise).

__launch_bounds__(256)
__global__ void gemm256_k(const float* __restrict__ X, const float* __restrict__ W,
                          const float* __restrict__ dinv, float* __restrict__ Y) {
  __shared__ float As[16][132];   // [k][row], padded to spread write banks
  __shared__ float Bs[16][128];   // [k][col]
  const int tid = threadIdx.x;
  const int n0 = (blockIdx.x & 1) * 128;
  const int m0 = (blockIdx.x >> 1) * 128;
  const int tx = tid & 15, ty = tid >> 4;

  float acc[8][8];
  #pragma unroll
  for (int i = 0; i < 8; ++i)
    #pragma unroll
    for (int j = 0; j < 8; ++j) acc[i][j] = 0.f;

  for (int k0 = 0; k0 < 256; k0 += 16) {
    #pragma unroll
    for (int l = 0; l < 2; ++l) {
      int f = tid + l * 256;
      int row = f >> 2, kq = (f & 3) << 2;
      int gr = m0 + row; if (gr > NNODES - 1) gr = NNODES - 1;
      float4 v = *reinterpret_cast<const float4*>(X + gr * 256 + k0 + kq);
      As[kq + 0][row] = v.x; As[kq + 1][row] = v.y;
      As[kq + 2][row] = v.z; As[kq + 3][row] = v.w;
    }
    #pragma unroll
    for (int l = 0; l < 2; ++l) {
      int f = tid + l * 256;
      int kk = f >> 5, colq = (f & 31) << 2;
      *reinterpret_cast<float4*>(&Bs[kk][colq]) =
          *reinterpret_cast<const float4*>(W + (k0 + kk) * 256 + n0 + colq);
    }
    __syncthreads();
    #pragma unroll
    for (int k = 0; k < 16; ++k) {
      float a[8], b[8];
      *reinterpret_cast<float4*>(&a[0]) = *reinterpret_cast<const float4*>(&As[k][ty * 4]);
      *reinterpret_cast<float4*>(&a[4]) = *reinterpret_cast<const float4*>(&As[k][ty * 4 + 64]);
      *reinterpret_cast<float4*>(&b[0]) = *reinterpret_cast<const float4*>(&Bs[k][tx * 4]);
      *reinterpret_cast<float4*>(&b[4]) = *reinterpret_cast<const float4*>(&Bs[k][tx * 4 + 64]);
      #pragma unroll
      for (int i = 0; i < 8; ++i)
        #pragma unroll
        for (int j = 0; j < 8; ++j) acc[i][j] += a[i] * b[j];
    }
    __syncthreads();
  }

  #pragma unroll
  for (int i = 0; i < 8; ++i) {
    int r = m0 + ty * 4 + (i < 4 ? i : 60 + i);   // 60+i == 64 + (i-4)
    if (r < NNODES) {
      float dv = dinv[r];
      float4 v0, v1;
      v0.x = acc[i][0] * dv; v0.y = acc[i][1] * dv; v0.z = acc[i][2] * dv; v0.w = acc[i][3] * dv;
      v1.x = acc[i][4] * dv; v1.y = acc[i][5] * dv; v1.z = acc[i][6] * dv; v1.w = acc[i][7] * dv;
      *reinterpret_cast<float4*>(Y + r * 256 + n0 + tx * 4) = v0;
      *reinterpret_cast<float4*>(Y + r * 256 + n0 + tx * 4 + 64) = v1;
    }
  }
}

// ---------------- gather: o[d] = relu(dinv[d]*(ys[d] + sum ys[src]) + b) ----------------
// one wave per node, 4 channels per lane.

__global__ void gather_k(const float* __restrict__ ys, const int* __restrict__ rs,
                         const int* __restrict__ csr, const float* __restrict__ dinv,
                         const float* __restrict__ bias, float* __restrict__ out) {
  int gt = blockIdx.x * blockDim.x + threadIdx.x;
  int d = gt >> 6;
  int c = (threadIdx.x & 63) << 2;
  float4 acc = *reinterpret_cast<const float4*>(ys + d * 256 + c);
  int e = rs[d], end = rs[d + 1];
  for (; e + 3 < end; e += 4) {
    int s0 = csr[e], s1 = csr[e + 1], s2 = csr[e + 2], s3 = csr[e + 3];
    float4 v0 = *reinterpret_cast<const float4*>(ys + s0 * 256 + c);
    float4 v1 = *reinterpret_cast<const float4*>(ys + s1 * 256 + c);
    float4 v2 = *reinterpret_cast<const float4*>(ys + s2 * 256 + c);
    float4 v3 = *reinterpret_cast<const float4*>(ys + s3 * 256 + c);
    acc.x += (v0.x + v1.x) + (v2.x + v3.x);
    acc.y += (v0.y + v1.y) + (v2.y + v3.y);
    acc.z += (v0.z + v1.z) + (v2.z + v3.z);
    acc.w += (v0.w + v1.w) + (v2.w + v3.w);
  }
  for (; e < end; ++e) {
    int s = csr[e];
    float4 v = *reinterpret_cast<const float4*>(ys + s * 256 + c);
    acc.x += v.x; acc.y += v.y; acc.z += v.z; acc.w += v.w;
  }
  float dv = dinv[d];
  float4 bb = *reinterpret_cast<const float4*>(bias + c);
  float4 o;
  o.x = fmaxf(acc.x * dv + bb.x, 0.f);
  o.y = fmaxf(acc.y * dv + bb.y, 0.f);
  o.z = fmaxf(acc.z * dv + bb.z, 0.f);
  o.w = fmaxf(acc.w * dv + bb.w, 0.f);
  *reinterpret_cast<float4*>(out + d * 256 + c) = o;
}

// ---------------- skern: h1acc[32 rows/block] += in @ lw  (lw: [256,32] slice of lin1_w) ----

__launch_bounds__(256)
__global__ void skern_k(const float* __restrict__ in, const float* __restrict__ lw,
                        float* __restrict__ h1acc) {
  __shared__ float os[32][256];
  int tid = threadIdx.x;
  int n0 = blockIdx.x * 32;
  #pragma unroll
  for (int l = 0; l < 8; ++l) {
    int f = tid + l * 256;
    int row = f >> 6, c4 = (f & 63) << 2;
    *reinterpret_cast<float4*>(&os[row][c4]) =
        *reinterpret_cast<const float4*>(in + (n0 + row) * 256 + c4);
  }
  __syncthreads();
  int dim = tid & 31, rblk = tid >> 5;
  float a0 = 0.f, a1 = 0.f, a2 = 0.f, a3 = 0.f;
  #pragma unroll 8
  for (int k = 0; k < 256; ++k) {
    float w = lw[k * 32 + dim];
    a0 += os[rblk * 4 + 0][k] * w;
    a1 += os[rblk * 4 + 1][k] * w;
    a2 += os[rblk * 4 + 2][k] * w;
    a3 += os[rblk * 4 + 3][k] * w;
  }
  int base = (n0 + rblk * 4) * 32 + dim;
  h1acc[base] += a0;
  h1acc[base + 32] += a1;
  h1acc[base + 64] += a2;
  h1acc[base + 96] += a3;
}

// ---------------- MLP: h2 = relu(relu(h1)@l2w + l2b), h1 = h1acc + action*w_last + l1b ----

__global__ void mlp_k(const float* __restrict__ h1acc, const float* __restrict__ action,
                      const float* __restrict__ l1wlast, const float* __restrict__ l1b,
                      const float* __restrict__ l2w, const float* __restrict__ l2b,
                      float* __restrict__ h2) {
  __shared__ float w2s[1024];
  __shared__ float h1s[8][33];
  int tid = threadIdx.x;
  #pragma unroll
  for (int i = tid; i < 1024; i += 256) w2s[i] = l2w[i];
  int dim = tid & 31, nl = tid >> 5;
  int n = blockIdx.x * 8 + nl;
  float h1 = h1acc[n * 32 + dim] + action[n] * l1wlast[dim] + l1b[dim];
  h1s[nl][dim] = fmaxf(h1, 0.f);
  __syncthreads();
  float acc = l2b[dim];
  #pragma unroll
  for (int k = 0; k < 32; ++k) acc += h1s[nl][k] * w2s[k * 32 + dim];
  h2[n * 32 + dim] = fmaxf(acc, 0.f);
}

// ---------------- readout: out[g] = sum_{a,dim} h2[g*192 + a*32+dim] * l3w[dim] + l3b ------

__global__ void final_k(const float* __restrict__ h2, const float* __restrict__ l3w,
                        const float* __restrict__ l3b, float* __restrict__ out) {
  int gt = blockIdx.x * blockDim.x + threadIdx.x;
  int g = gt >> 6, lane = threadIdx.x & 63;
  float s = 0.f;
  #pragma unroll
  for (int p0 = 0; p0 < 192; p0 += 64) {
    int p = p0 + lane;
    s += h2[g * 192 + p] * l3w[p & 31];
  }
  #pragma unroll
  for (int off = 32; off; off >>= 1) s += __shfl_down(s, off, 64);
  if (lane == 0) out[g] = s + l3b[0];
}

// ---------------- host ----------------

extern "C" void kernel_launch(void* const* d_in, const int* in_sizes, int n_in,
                              void* d_out, int out_size, void* d_ws, size_t ws_size,
                              hipStream_t stream) {
  const float* state  = (const float*)d_in[0];
  const int*   ei     = (const int*)d_in[1];
  const float* action = (const float*)d_in[2];
  const float* W1 = (const float*)d_in[3];
  const float* b1 = (const float*)d_in[4];
  const float* W2 = (const float*)d_in[5];
  const float* b2 = (const float*)d_in[6];
  const float* W3 = (const float*)d_in[7];
  const float* b3 = (const float*)d_in[8];
  const float* l1w = (const float*)d_in[13];
  const float* l1b = (const float*)d_in[14];
  const float* l2w = (const float*)d_in[15];
  const float* l2b = (const float*)d_in[16];
  const float* l3w = (const float*)d_in[17];
  const float* l3b = (const float*)d_in[18];
  float* out = (float*)d_out;

  char* base = (char*)d_ws;
  size_t off = 0;
  auto carve = [&](size_t bytes) {
    char* q = base + off;
    off += (bytes + 255) & ~(size_t)255;
    return q;
  };
  float* ys    = (float*)carve((size_t)NNODES * 256 * 4);
  float* obuf  = (float*)carve((size_t)NNODES * 256 * 4);
  float* h1acc = (float*)carve((size_t)NNODES * 32 * 4);
  float* h2    = (float*)carve((size_t)NNODES * 32 * 4);
  float* dinv  = (float*)carve(NNODES * 4);
  int*   deg   = (int*)carve(NNODES * 4);
  int*   rs    = (int*)carve((NNODES + 1) * 4);
  int*   cursor= (int*)carve(NNODES * 4);
  int*   csr   = (int*)carve((size_t)NEDGES * 4);
  int*   bsum  = (int*)carve(256 * 4);

  hipMemsetAsync(deg, 0, NNODES * 4, stream);
  hipMemsetAsync(cursor, 0, NNODES * 4, stream);
  hipMemsetAsync(h1acc, 0, (size_t)NNODES * 32 * 4, stream);

  count_deg_k<<<NEDGES / 256, 256, 0, stream>>>(ei, deg);
  dinv_k<<<(NNODES + 255) / 256, 256, 0, stream>>>(deg, dinv);
  int nb = (NNODES + 255) / 256;  // 235
  scan1_k<<<nb, 256, 0, stream>>>(deg, rs, bsum);
  scan2_k<<<1, 256, 0, stream>>>(bsum, nb);
  scan3_k<<<nb, 256, 0, stream>>>(rs, bsum);
  scatter_k<<<NEDGES / 256, 256, 0, stream>>>(ei, rs, cursor, csr);

  const float* Ws[5] = {W1, W2, W3, W3, W3};
  const float* bs[5] = {b1, b2, b3, b3, b3};
  const float* in = state;
  for (int layer = 0; layer < 5; ++layer) {
    gemm256_k<<<469 * 2, 256, 0, stream>>>(in, Ws[layer], dinv, ys);
    gather_k<<<NNODES / 4, 256, 0, stream>>>(ys, rs, csr, dinv, bs[layer], obuf);
    skern_k<<<NNODES / 32, 256, 0, stream>>>(obuf, l1w + layer * 256 * 32, h1acc);
    in = obuf;
  }
  skern_k<<<NNODES / 32, 256, 0, stream>>>(state, l1w + 1280 * 32, h1acc);
  mlp_k<<<NNODES / 8, 256, 0, stream>>>(h1acc, action, l1w + 1536 * 32, l1b, l2w, l2b, h2);
  final_k<<<NGRAPH / 4, 256, 0, stream>>>(h2, l3w, l3b, out);
}

// Round 2
// 1186.560 us; speedup vs baseline: 1.3022x; 1.3022x over previous
//
#include <hip/hip_runtime.h>
#include <hip/hip_fp16.h>

#define NNODES 60000
#define NEDGES 960000
#define NGRAPH 10000

struct __align__(16) H8 { __half2 h[4]; };
struct __align__(8)  H4 { __half2 h[2]; };

// ---------------- degree / CSR build ----------------

__global__ void count_deg_k(const int* __restrict__ ei, int* __restrict__ deg) {
  int e = blockIdx.x * blockDim.x + threadIdx.x;
  atomicAdd(&deg[ei[NEDGES + e]], 1);
}

__global__ void dinv_k(const int* __restrict__ deg, float* __restrict__ dinv) {
  int i = blockIdx.x * blockDim.x + threadIdx.x;
  if (i < NNODES) dinv[i] = rsqrtf((float)deg[i] + 1.0f);
}

__global__ void scan1_k(const int* __restrict__ deg, int* __restrict__ rs, int* __restrict__ bsum) {
  __shared__ int s[256];
  int tid = threadIdx.x;
  int i = blockIdx.x * 256 + tid;
  int v = (i < NNODES) ? deg[i] : 0;
  int x = v;
  s[tid] = x; __syncthreads();
  #pragma unroll
  for (int off = 1; off < 256; off <<= 1) {
    int t = (tid >= off) ? s[tid - off] : 0;
    __syncthreads();
    x += t; s[tid] = x; __syncthreads();
  }
  if (i < NNODES) rs[i] = x - v;
  if (tid == 255) bsum[blockIdx.x] = x;
}

__global__ void scan2_k(int* __restrict__ bsum, int nb) {
  __shared__ int s[256];
  int tid = threadIdx.x;
  int v = (tid < nb) ? bsum[tid] : 0;
  int x = v; s[tid] = x; __syncthreads();
  #pragma unroll
  for (int off = 1; off < 256; off <<= 1) {
    int t = (tid >= off) ? s[tid - off] : 0;
    __syncthreads();
    x += t; s[tid] = x; __syncthreads();
  }
  if (tid < nb) bsum[tid] = x - v;
}

__global__ void scan3_k(int* __restrict__ rs, const int* __restrict__ bsum) {
  int i = blockIdx.x * 256 + threadIdx.x;
  if (i < NNODES) rs[i] += bsum[blockIdx.x];
  if (i == 0) rs[NNODES] = NEDGES;
}

__global__ void scatter_k(const int* __restrict__ ei, const int* __restrict__ rs,
                          int* __restrict__ cursor, int* __restrict__ csr) {
  int e = blockIdx.x * blockDim.x + threadIdx.x;
  int s = ei[e], d = ei[NEDGES + e];
  int pos = rs[d] + atomicAdd(&cursor[d], 1);
  csr[pos] = s;
}

// ---------------- GEMM: Yh[r] = fp16((X @ W)[r] * dinv[r]),  X:[M,256] W:[256,256] --------
// 128x128 tile, BK=16, 8x8 micro-tile per thread.

__launch_bounds__(256)
__global__ void gemm256_k(const float* __restrict__ X, const float* __restrict__ W,
                          const float* __restrict__ dinv, __half* __restrict__ Y) {
  __shared__ float As[16][132];
  __shared__ float Bs[16][128];
  const int tid = threadIdx.x;
  const int n0 = (blockIdx.x & 1) * 128;
  const int m0 = (blockIdx.x >> 1) * 128;
  const int tx = tid & 15, ty = tid >> 4;

  float acc[8][8];
  #pragma unroll
  for (int i = 0; i < 8; ++i)
    #pragma unroll
    for (int j = 0; j < 8; ++j) acc[i][j] = 0.f;

  for (int k0 = 0; k0 < 256; k0 += 16) {
    #pragma unroll
    for (int l = 0; l < 2; ++l) {
      int f = tid + l * 256;
      int row = f >> 2, kq = (f & 3) << 2;
      int gr = m0 + row; if (gr > NNODES - 1) gr = NNODES - 1;
      float4 v = *reinterpret_cast<const float4*>(X + gr * 256 + k0 + kq);
      As[kq + 0][row] = v.x; As[kq + 1][row] = v.y;
      As[kq + 2][row] = v.z; As[kq + 3][row] = v.w;
    }
    #pragma unroll
    for (int l = 0; l < 2; ++l) {
      int f = tid + l * 256;
      int kk = f >> 5, colq = (f & 31) << 2;
      *reinterpret_cast<float4*>(&Bs[kk][colq]) =
          *reinterpret_cast<const float4*>(W + (k0 + kk) * 256 + n0 + colq);
    }
    __syncthreads();
    #pragma unroll
    for (int k = 0; k < 16; ++k) {
      float a[8], b[8];
      *reinterpret_cast<float4*>(&a[0]) = *reinterpret_cast<const float4*>(&As[k][ty * 4]);
      *reinterpret_cast<float4*>(&a[4]) = *reinterpret_cast<const float4*>(&As[k][ty * 4 + 64]);
      *reinterpret_cast<float4*>(&b[0]) = *reinterpret_cast<const float4*>(&Bs[k][tx * 4]);
      *reinterpret_cast<float4*>(&b[4]) = *reinterpret_cast<const float4*>(&Bs[k][tx * 4 + 64]);
      #pragma unroll
      for (int i = 0; i < 8; ++i)
        #pragma unroll
        for (int j = 0; j < 8; ++j) acc[i][j] += a[i] * b[j];
    }
    __syncthreads();
  }

  #pragma unroll
  for (int i = 0; i < 8; ++i) {
    int r = m0 + ty * 4 + (i < 4 ? i : 60 + i);
    if (r < NNODES) {
      float dv = dinv[r];
      H4 lo, hi;
      #pragma unroll
      for (int q = 0; q < 2; ++q) {
        __half2 p;
        p.x = __float2half_rn(acc[i][q * 2 + 0] * dv);
        p.y = __float2half_rn(acc[i][q * 2 + 1] * dv);
        lo.h[q] = p;
        __half2 r2;
        r2.x = __float2half_rn(acc[i][4 + q * 2 + 0] * dv);
        r2.y = __float2half_rn(acc[i][4 + q * 2 + 1] * dv);
        hi.h[q] = r2;
      }
      *reinterpret_cast<H4*>(Y + (size_t)r * 256 + n0 + tx * 4) = lo;
      *reinterpret_cast<H4*>(Y + (size_t)r * 256 + n0 + tx * 4 + 64) = hi;
    }
  }
}

// ---------------- gather: o[d] = relu(dinv[d]*(ys[d] + sum ys[src]) + b) ----------------
// half-wave (32 lanes) per node; 8 fp16 channels per lane via one 16B load.

__device__ inline void addH8(float* acc, const H8& v) {
  #pragma unroll
  for (int q = 0; q < 4; ++q) {
    acc[q * 2 + 0] += __low2float(v.h[q]);
    acc[q * 2 + 1] += __high2float(v.h[q]);
  }
}

__global__ void gather_k(const __half* __restrict__ ysh, const int* __restrict__ rs,
                         const int* __restrict__ csr, const float* __restrict__ dinv,
                         const float* __restrict__ bias, float* __restrict__ out) {
  int tid = threadIdx.x;
  int lane = tid & 63;
  int wave = (blockIdx.x * blockDim.x + tid) >> 6;
  int d = wave * 2 + (lane >> 5);
  int c8 = (lane & 31) * 8;

  float acc[8];
  H8 self = *reinterpret_cast<const H8*>(ysh + (size_t)d * 256 + c8);
  #pragma unroll
  for (int q = 0; q < 4; ++q) {
    acc[q * 2 + 0] = __low2float(self.h[q]);
    acc[q * 2 + 1] = __high2float(self.h[q]);
  }

  int e = rs[d], end = rs[d + 1];
  for (; e + 1 < end; e += 2) {
    int s0 = csr[e], s1 = csr[e + 1];
    H8 v0 = *reinterpret_cast<const H8*>(ysh + (size_t)s0 * 256 + c8);
    H8 v1 = *reinterpret_cast<const H8*>(ysh + (size_t)s1 * 256 + c8);
    addH8(acc, v0);
    addH8(acc, v1);
  }
  if (e < end) {
    int s0 = csr[e];
    H8 v0 = *reinterpret_cast<const H8*>(ysh + (size_t)s0 * 256 + c8);
    addH8(acc, v0);
  }

  float dv = dinv[d];
  float4 b0 = *reinterpret_cast<const float4*>(bias + c8);
  float4 b1 = *reinterpret_cast<const float4*>(bias + c8 + 4);
  float4 o0, o1;
  o0.x = fmaxf(acc[0] * dv + b0.x, 0.f);
  o0.y = fmaxf(acc[1] * dv + b0.y, 0.f);
  o0.z = fmaxf(acc[2] * dv + b0.z, 0.f);
  o0.w = fmaxf(acc[3] * dv + b0.w, 0.f);
  o1.x = fmaxf(acc[4] * dv + b1.x, 0.f);
  o1.y = fmaxf(acc[5] * dv + b1.y, 0.f);
  o1.z = fmaxf(acc[6] * dv + b1.z, 0.f);
  o1.w = fmaxf(acc[7] * dv + b1.w, 0.f);
  float* op = out + (size_t)d * 256 + c8;
  *reinterpret_cast<float4*>(op) = o0;
  *reinterpret_cast<float4*>(op + 4) = o1;
}

// ---------------- skern: h1acc[32 rows/block] += in @ lw ----------------

__launch_bounds__(256)
__global__ void skern_k(const float* __restrict__ in, const float* __restrict__ lw,
                        float* __restrict__ h1acc) {
  __shared__ float os[32][256];
  int tid = threadIdx.x;
  int n0 = blockIdx.x * 32;
  #pragma unroll
  for (int l = 0; l < 8; ++l) {
    int f = tid + l * 256;
    int row = f >> 6, c4 = (f & 63) << 2;
    *reinterpret_cast<float4*>(&os[row][c4]) =
        *reinterpret_cast<const float4*>(in + (size_t)(n0 + row) * 256 + c4);
  }
  __syncthreads();
  int dim = tid & 31, rblk = tid >> 5;
  float a0 = 0.f, a1 = 0.f, a2 = 0.f, a3 = 0.f;
  #pragma unroll 8
  for (int k = 0; k < 256; ++k) {
    float w = lw[k * 32 + dim];
    a0 += os[rblk * 4 + 0][k] * w;
    a1 += os[rblk * 4 + 1][k] * w;
    a2 += os[rblk * 4 + 2][k] * w;
    a3 += os[rblk * 4 + 3][k] * w;
  }
  int base = (n0 + rblk * 4) * 32 + dim;
  h1acc[base] += a0;
  h1acc[base + 32] += a1;
  h1acc[base + 64] += a2;
  h1acc[base + 96] += a3;
}

// ---------------- MLP ----------------

__global__ void mlp_k(const float* __restrict__ h1acc, const float* __restrict__ action,
                      const float* __restrict__ l1wlast, const float* __restrict__ l1b,
                      const float* __restrict__ l2w, const float* __restrict__ l2b,
                      float* __restrict__ h2) {
  __shared__ float w2s[1024];
  __shared__ float h1s[8][33];
  int tid = threadIdx.x;
  #pragma unroll
  for (int i = tid; i < 1024; i += 256) w2s[i] = l2w[i];
  int dim = tid & 31, nl = tid >> 5;
  int n = blockIdx.x * 8 + nl;
  float h1 = h1acc[n * 32 + dim] + action[n] * l1wlast[dim] + l1b[dim];
  h1s[nl][dim] = fmaxf(h1, 0.f);
  __syncthreads();
  float acc = l2b[dim];
  #pragma unroll
  for (int k = 0; k < 32; ++k) acc += h1s[nl][k] * w2s[k * 32 + dim];
  h2[n * 32 + dim] = fmaxf(acc, 0.f);
}

// ---------------- readout ----------------

__global__ void final_k(const float* __restrict__ h2, const float* __restrict__ l3w,
                        const float* __restrict__ l3b, float* __restrict__ out) {
  int gt = blockIdx.x * blockDim.x + threadIdx.x;
  int g = gt >> 6, lane = threadIdx.x & 63;
  float s = 0.f;
  #pragma unroll
  for (int p0 = 0; p0 < 192; p0 += 64) {
    int p = p0 + lane;
    s += h2[g * 192 + p] * l3w[p & 31];
  }
  #pragma unroll
  for (int off = 32; off; off >>= 1) s += __shfl_down(s, off, 64);
  if (lane == 0) out[g] = s + l3b[0];
}

// ---------------- host ----------------

extern "C" void kernel_launch(void* const* d_in, const int* in_sizes, int n_in,
                              void* d_out, int out_size, void* d_ws, size_t ws_size,
                              hipStream_t stream) {
  const float* state  = (const float*)d_in[0];
  const int*   ei     = (const int*)d_in[1];
  const float* action = (const float*)d_in[2];
  const float* W1 = (const float*)d_in[3];
  const float* b1 = (const float*)d_in[4];
  const float* W2 = (const float*)d_in[5];
  const float* b2 = (const float*)d_in[6];
  const float* W3 = (const float*)d_in[7];
  const float* b3 = (const float*)d_in[8];
  const float* l1w = (const float*)d_in[13];
  const float* l1b = (const float*)d_in[14];
  const float* l2w = (const float*)d_in[15];
  const float* l2b = (const float*)d_in[16];
  const float* l3w = (const float*)d_in[17];
  const float* l3b = (const float*)d_in[18];
  float* out = (float*)d_out;

  char* base = (char*)d_ws;
  size_t off = 0;
  auto carve = [&](size_t bytes) {
    char* q = base + off;
    off += (bytes + 255) & ~(size_t)255;
    return q;
  };
  __half* ysh  = (__half*)carve((size_t)NNODES * 256 * 2);
  float* obuf  = (float*)carve((size_t)NNODES * 256 * 4);
  float* h1acc = (float*)carve((size_t)NNODES * 32 * 4);
  float* h2    = (float*)carve((size_t)NNODES * 32 * 4);
  float* dinv  = (float*)carve(NNODES * 4);
  int*   deg   = (int*)carve(NNODES * 4);
  int*   rs    = (int*)carve((NNODES + 1) * 4);
  int*   cursor= (int*)carve(NNODES * 4);
  int*   csr   = (int*)carve((size_t)NEDGES * 4);
  int*   bsum  = (int*)carve(256 * 4);

  hipMemsetAsync(deg, 0, NNODES * 4, stream);
  hipMemsetAsync(cursor, 0, NNODES * 4, stream);
  hipMemsetAsync(h1acc, 0, (size_t)NNODES * 32 * 4, stream);

  count_deg_k<<<NEDGES / 256, 256, 0, stream>>>(ei, deg);
  dinv_k<<<(NNODES + 255) / 256, 256, 0, stream>>>(deg, dinv);
  int nb = (NNODES + 255) / 256;
  scan1_k<<<nb, 256, 0, stream>>>(deg, rs, bsum);
  scan2_k<<<1, 256, 0, stream>>>(bsum, nb);
  scan3_k<<<nb, 256, 0, stream>>>(rs, bsum);
  scatter_k<<<NEDGES / 256, 256, 0, stream>>>(ei, rs, cursor, csr);

  const float* Ws[5] = {W1, W2, W3, W3, W3};
  const float* bs[5] = {b1, b2, b3, b3, b3};
  const float* in = state;
  for (int layer = 0; layer < 5; ++layer) {
    gemm256_k<<<469 * 2, 256, 0, stream>>>(in, Ws[layer], dinv, ysh);
    gather_k<<<NNODES / 8, 256, 0, stream>>>(ysh, rs, csr, dinv, bs[layer], obuf);
    skern_k<<<NNODES / 32, 256, 0, stream>>>(obuf, l1w + layer * 256 * 32, h1acc);
    in = obuf;
  }
  skern_k<<<NNODES / 32, 256, 0, stream>>>(state, l1w + 1280 * 32, h1acc);
  mlp_k<<<NNODES / 8, 256, 0, stream>>>(h1acc, action, l1w + 1536 * 32, l1b, l2w, l2b, h2);
  final_k<<<NGRAPH / 4, 256, 0, stream>>>(h2, l3w, l3b, out);
}

// Round 3
// 806.252 us; speedup vs baseline: 1.9164x; 1.4717x over previous
//
#include <hip/hip_runtime.h>
#include <hip/hip_fp16.h>

#define NNODES 60000
#define NEDGES 960000
#define NGRAPH 10000

struct __align__(16) H8 { __half2 h[4]; };
struct __align__(8)  H4 { __half2 h[2]; };

typedef _Float16 f16x8 __attribute__((ext_vector_type(8)));
typedef float f32x4 __attribute__((ext_vector_type(4)));

// ---------------- degree / CSR build ----------------

__global__ void count_deg_k(const int* __restrict__ ei, int* __restrict__ deg) {
  int e = blockIdx.x * blockDim.x + threadIdx.x;
  atomicAdd(&deg[ei[NEDGES + e]], 1);
}

__global__ void dinv_k(const int* __restrict__ deg, float* __restrict__ dinv) {
  int i = blockIdx.x * blockDim.x + threadIdx.x;
  if (i < NNODES) dinv[i] = rsqrtf((float)deg[i] + 1.0f);
}

__global__ void scan1_k(const int* __restrict__ deg, int* __restrict__ rs, int* __restrict__ bsum) {
  __shared__ int s[256];
  int tid = threadIdx.x;
  int i = blockIdx.x * 256 + tid;
  int v = (i < NNODES) ? deg[i] : 0;
  int x = v;
  s[tid] = x; __syncthreads();
  #pragma unroll
  for (int off = 1; off < 256; off <<= 1) {
    int t = (tid >= off) ? s[tid - off] : 0;
    __syncthreads();
    x += t; s[tid] = x; __syncthreads();
  }
  if (i < NNODES) rs[i] = x - v;
  if (tid == 255) bsum[blockIdx.x] = x;
}

__global__ void scan2_k(int* __restrict__ bsum, int nb) {
  __shared__ int s[256];
  int tid = threadIdx.x;
  int v = (tid < nb) ? bsum[tid] : 0;
  int x = v; s[tid] = x; __syncthreads();
  #pragma unroll
  for (int off = 1; off < 256; off <<= 1) {
    int t = (tid >= off) ? s[tid - off] : 0;
    __syncthreads();
    x += t; s[tid] = x; __syncthreads();
  }
  if (tid < nb) bsum[tid] = x - v;
}

__global__ void scan3_k(int* __restrict__ rs, const int* __restrict__ bsum) {
  int i = blockIdx.x * 256 + threadIdx.x;
  if (i < NNODES) rs[i] += bsum[blockIdx.x];
  if (i == 0) rs[NNODES] = NEDGES;
}

__global__ void scatter_k(const int* __restrict__ ei, const int* __restrict__ rs,
                          int* __restrict__ cursor, int* __restrict__ csr) {
  int e = blockIdx.x * blockDim.x + threadIdx.x;
  int s = ei[e], d = ei[NEDGES + e];
  int pos = rs[d] + atomicAdd(&cursor[d], 1);
  csr[pos] = s;
}

// ---------------- fp32 -> fp16 convert (state) ----------------

__global__ void f2h_k(const float* __restrict__ in, __half* __restrict__ out) {
  int i = blockIdx.x * blockDim.x + threadIdx.x;   // one H8 per thread
  float4 a = *reinterpret_cast<const float4*>(in + (size_t)i * 8);
  float4 b = *reinterpret_cast<const float4*>(in + (size_t)i * 8 + 4);
  H8 o;
  o.h[0].x = __float2half_rn(a.x); o.h[0].y = __float2half_rn(a.y);
  o.h[1].x = __float2half_rn(a.z); o.h[1].y = __float2half_rn(a.w);
  o.h[2].x = __float2half_rn(b.x); o.h[2].y = __float2half_rn(b.y);
  o.h[3].x = __float2half_rn(b.z); o.h[3].y = __float2half_rn(b.w);
  *reinterpret_cast<H8*>(out + (size_t)i * 8) = o;
}

// ---------------- weight transpose+convert: WhT[n][k] = fp16(W[k][n]) ----------------

__global__ void wconv_k(const float* __restrict__ W, __half* __restrict__ WhT) {
  int n = blockIdx.x, k = threadIdx.x;
  WhT[n * 256 + k] = __float2half_rn(W[k * 256 + n]);
}

// ---------------- MFMA GEMM: Y[r] = fp16((X @ W)[r] * dinv[r]) ----------------
// 128x128 tile, BK=32, 4 waves (2x2), each wave 64x64 via 4x4 frags of 16x16x32 f16.
// Swapped operands: mfma(b,a,acc) -> lane holds 4 consecutive output cols per frag.

#define LDP 56   // LDS row stride in halves: 112 B = 28 banks -> 2-way (free), 16B-aligned

__launch_bounds__(256)
__global__ void gemm_mfma_k(const __half* __restrict__ Xh, const __half* __restrict__ WhT,
                            const float* __restrict__ dinv, __half* __restrict__ Y) {
  __shared__ _Float16 As[128][LDP];
  __shared__ _Float16 Bs[128][LDP];
  const int tid = threadIdx.x;
  const int n0 = (blockIdx.x & 1) * 128;
  const int m0 = (blockIdx.x >> 1) * 128;
  const int lane = tid & 63;
  const int wid = tid >> 6;
  const int wr = wid >> 1, wc = wid & 1;
  const int li = lane & 15, lg = lane >> 4;

  f32x4 acc[4][4];
  #pragma unroll
  for (int i = 0; i < 4; ++i)
    #pragma unroll
    for (int j = 0; j < 4; ++j) acc[i][j] = (f32x4){0.f, 0.f, 0.f, 0.f};

  for (int k0 = 0; k0 < 256; k0 += 32) {
    #pragma unroll
    for (int l = 0; l < 2; ++l) {
      int f = tid + l * 256;
      int row = f >> 2, cq = (f & 3) * 8;
      int gr = m0 + row; if (gr >= NNODES) gr = NNODES - 1;
      *reinterpret_cast<H8*>(&As[row][cq]) =
          *reinterpret_cast<const H8*>(Xh + (size_t)gr * 256 + k0 + cq);
      *reinterpret_cast<H8*>(&Bs[row][cq]) =
          *reinterpret_cast<const H8*>(WhT + (size_t)(n0 + row) * 256 + k0 + cq);
    }
    __syncthreads();
    f16x8 a[4], b[4];
    #pragma unroll
    for (int rf = 0; rf < 4; ++rf)
      a[rf] = *reinterpret_cast<const f16x8*>(&As[wr * 64 + rf * 16 + li][lg * 8]);
    #pragma unroll
    for (int cf = 0; cf < 4; ++cf)
      b[cf] = *reinterpret_cast<const f16x8*>(&Bs[wc * 64 + cf * 16 + li][lg * 8]);
    #pragma unroll
    for (int rf = 0; rf < 4; ++rf)
      #pragma unroll
      for (int cf = 0; cf < 4; ++cf)
        acc[rf][cf] = __builtin_amdgcn_mfma_f32_16x16x32_f16(b[cf], a[rf], acc[rf][cf], 0, 0, 0);
    __syncthreads();
  }

  #pragma unroll
  for (int rf = 0; rf < 4; ++rf) {
    int r = m0 + wr * 64 + rf * 16 + li;
    if (r < NNODES) {
      float dv = dinv[r];
      #pragma unroll
      for (int cf = 0; cf < 4; ++cf) {
        int n = n0 + wc * 64 + cf * 16 + lg * 4;
        H4 o;
        o.h[0].x = __float2half_rn(acc[rf][cf][0] * dv);
        o.h[0].y = __float2half_rn(acc[rf][cf][1] * dv);
        o.h[1].x = __float2half_rn(acc[rf][cf][2] * dv);
        o.h[1].y = __float2half_rn(acc[rf][cf][3] * dv);
        *reinterpret_cast<H4*>(Y + (size_t)r * 256 + n) = o;
      }
    }
  }
}

// ---------------- gather: o[d] = fp16(relu(dinv[d]*(ys[d] + sum ys[src]) + b)) ----------

__device__ inline void addH8(float* acc, const H8& v) {
  #pragma unroll
  for (int q = 0; q < 4; ++q) {
    acc[q * 2 + 0] += __low2float(v.h[q]);
    acc[q * 2 + 1] += __high2float(v.h[q]);
  }
}

__global__ void gather_k(const __half* __restrict__ ysh, const int* __restrict__ rs,
                         const int* __restrict__ csr, const float* __restrict__ dinv,
                         const float* __restrict__ bias, __half* __restrict__ out) {
  int tid = threadIdx.x;
  int lane = tid & 63;
  int wave = (blockIdx.x * blockDim.x + tid) >> 6;
  int d = wave * 2 + (lane >> 5);
  int c8 = (lane & 31) * 8;

  float acc[8];
  H8 self = *reinterpret_cast<const H8*>(ysh + (size_t)d * 256 + c8);
  #pragma unroll
  for (int q = 0; q < 4; ++q) {
    acc[q * 2 + 0] = __low2float(self.h[q]);
    acc[q * 2 + 1] = __high2float(self.h[q]);
  }

  int e = rs[d], end = rs[d + 1];
  for (; e + 1 < end; e += 2) {
    int s0 = csr[e], s1 = csr[e + 1];
    H8 v0 = *reinterpret_cast<const H8*>(ysh + (size_t)s0 * 256 + c8);
    H8 v1 = *reinterpret_cast<const H8*>(ysh + (size_t)s1 * 256 + c8);
    addH8(acc, v0);
    addH8(acc, v1);
  }
  if (e < end) {
    int s0 = csr[e];
    H8 v0 = *reinterpret_cast<const H8*>(ysh + (size_t)s0 * 256 + c8);
    addH8(acc, v0);
  }

  float dv = dinv[d];
  float4 b0 = *reinterpret_cast<const float4*>(bias + c8);
  float4 b1 = *reinterpret_cast<const float4*>(bias + c8 + 4);
  float r0 = fmaxf(acc[0] * dv + b0.x, 0.f);
  float r1 = fmaxf(acc[1] * dv + b0.y, 0.f);
  float r2 = fmaxf(acc[2] * dv + b0.z, 0.f);
  float r3 = fmaxf(acc[3] * dv + b0.w, 0.f);
  float r4 = fmaxf(acc[4] * dv + b1.x, 0.f);
  float r5 = fmaxf(acc[5] * dv + b1.y, 0.f);
  float r6 = fmaxf(acc[6] * dv + b1.z, 0.f);
  float r7 = fmaxf(acc[7] * dv + b1.w, 0.f);
  H8 o;
  o.h[0].x = __float2half_rn(r0); o.h[0].y = __float2half_rn(r1);
  o.h[1].x = __float2half_rn(r2); o.h[1].y = __float2half_rn(r3);
  o.h[2].x = __float2half_rn(r4); o.h[2].y = __float2half_rn(r5);
  o.h[3].x = __float2half_rn(r6); o.h[3].y = __float2half_rn(r7);
  *reinterpret_cast<H8*>(out + (size_t)d * 256 + c8) = o;
}

// ---------------- skern: h1acc[32 rows/block] += in @ lw  (in fp16) ----------------

__launch_bounds__(256)
__global__ void skern_k(const __half* __restrict__ in, const float* __restrict__ lw,
                        float* __restrict__ h1acc) {
  __shared__ float os[32][256];
  int tid = threadIdx.x;
  int n0 = blockIdx.x * 32;
  #pragma unroll
  for (int l = 0; l < 4; ++l) {
    int f = tid + l * 256;
    int row = f >> 5, c8 = (f & 31) * 8;
    H8 v = *reinterpret_cast<const H8*>(in + (size_t)(n0 + row) * 256 + c8);
    float* dst = &os[row][c8];
    dst[0] = __low2float(v.h[0]); dst[1] = __high2float(v.h[0]);
    dst[2] = __low2float(v.h[1]); dst[3] = __high2float(v.h[1]);
    dst[4] = __low2float(v.h[2]); dst[5] = __high2float(v.h[2]);
    dst[6] = __low2float(v.h[3]); dst[7] = __high2float(v.h[3]);
  }
  __syncthreads();
  int dim = tid & 31, rblk = tid >> 5;
  float a0 = 0.f, a1 = 0.f, a2 = 0.f, a3 = 0.f;
  #pragma unroll 8
  for (int k = 0; k < 256; ++k) {
    float w = lw[k * 32 + dim];
    a0 += os[rblk * 4 + 0][k] * w;
    a1 += os[rblk * 4 + 1][k] * w;
    a2 += os[rblk * 4 + 2][k] * w;
    a3 += os[rblk * 4 + 3][k] * w;
  }
  int base = (n0 + rblk * 4) * 32 + dim;
  h1acc[base] += a0;
  h1acc[base + 32] += a1;
  h1acc[base + 64] += a2;
  h1acc[base + 96] += a3;
}

// ---------------- MLP ----------------

__global__ void mlp_k(const float* __restrict__ h1acc, const float* __restrict__ action,
                      const float* __restrict__ l1wlast, const float* __restrict__ l1b,
                      const float* __restrict__ l2w, const float* __restrict__ l2b,
                      float* __restrict__ h2) {
  __shared__ float w2s[1024];
  __shared__ float h1s[8][33];
  int tid = threadIdx.x;
  #pragma unroll
  for (int i = tid; i < 1024; i += 256) w2s[i] = l2w[i];
  int dim = tid & 31, nl = tid >> 5;
  int n = blockIdx.x * 8 + nl;
  float h1 = h1acc[n * 32 + dim] + action[n] * l1wlast[dim] + l1b[dim];
  h1s[nl][dim] = fmaxf(h1, 0.f);
  __syncthreads();
  float acc = l2b[dim];
  #pragma unroll
  for (int k = 0; k < 32; ++k) acc += h1s[nl][k] * w2s[k * 32 + dim];
  h2[n * 32 + dim] = fmaxf(acc, 0.f);
}

// ---------------- readout ----------------

__global__ void final_k(const float* __restrict__ h2, const float* __restrict__ l3w,
                        const float* __restrict__ l3b, float* __restrict__ out) {
  int gt = blockIdx.x * blockDim.x + threadIdx.x;
  int g = gt >> 6, lane = threadIdx.x & 63;
  float s = 0.f;
  #pragma unroll
  for (int p0 = 0; p0 < 192; p0 += 64) {
    int p = p0 + lane;
    s += h2[g * 192 + p] * l3w[p & 31];
  }
  #pragma unroll
  for (int off = 32; off; off >>= 1) s += __shfl_down(s, off, 64);
  if (lane == 0) out[g] = s + l3b[0];
}

// ---------------- host ----------------

extern "C" void kernel_launch(void* const* d_in, const int* in_sizes, int n_in,
                              void* d_out, int out_size, void* d_ws, size_t ws_size,
                              hipStream_t stream) {
  const float* state  = (const float*)d_in[0];
  const int*   ei     = (const int*)d_in[1];
  const float* action = (const float*)d_in[2];
  const float* W1 = (const float*)d_in[3];
  const float* b1 = (const float*)d_in[4];
  const float* W2 = (const float*)d_in[5];
  const float* b2 = (const float*)d_in[6];
  const float* W3 = (const float*)d_in[7];
  const float* b3 = (const float*)d_in[8];
  const float* l1w = (const float*)d_in[13];
  const float* l1b = (const float*)d_in[14];
  const float* l2w = (const float*)d_in[15];
  const float* l2b = (const float*)d_in[16];
  const float* l3w = (const float*)d_in[17];
  const float* l3b = (const float*)d_in[18];
  float* out = (float*)d_out;

  char* base = (char*)d_ws;
  size_t off = 0;
  auto carve = [&](size_t bytes) {
    char* q = base + off;
    off += (bytes + 255) & ~(size_t)255;
    return q;
  };
  __half* ysh    = (__half*)carve((size_t)NNODES * 256 * 2);
  __half* obufh  = (__half*)carve((size_t)NNODES * 256 * 2);
  __half* stateh = (__half*)carve((size_t)NNODES * 256 * 2);
  __half* whT1   = (__half*)carve(256 * 256 * 2);
  __half* whT2   = (__half*)carve(256 * 256 * 2);
  __half* whT3   = (__half*)carve(256 * 256 * 2);
  float* h1acc = (float*)carve((size_t)NNODES * 32 * 4);
  float* h2    = (float*)carve((size_t)NNODES * 32 * 4);
  float* dinv  = (float*)carve(NNODES * 4);
  int*   deg   = (int*)carve(NNODES * 4);
  int*   rs    = (int*)carve((NNODES + 1) * 4);
  int*   cursor= (int*)carve(NNODES * 4);
  int*   csr   = (int*)carve((size_t)NEDGES * 4);
  int*   bsum  = (int*)carve(256 * 4);

  hipMemsetAsync(deg, 0, NNODES * 4, stream);
  hipMemsetAsync(cursor, 0, NNODES * 4, stream);
  hipMemsetAsync(h1acc, 0, (size_t)NNODES * 32 * 4, stream);

  f2h_k<<<(NNODES * 256 / 8) / 256, 256, 0, stream>>>(state, stateh);
  wconv_k<<<256, 256, 0, stream>>>(W1, whT1);
  wconv_k<<<256, 256, 0, stream>>>(W2, whT2);
  wconv_k<<<256, 256, 0, stream>>>(W3, whT3);

  count_deg_k<<<NEDGES / 256, 256, 0, stream>>>(ei, deg);
  dinv_k<<<(NNODES + 255) / 256, 256, 0, stream>>>(deg, dinv);
  int nb = (NNODES + 255) / 256;
  scan1_k<<<nb, 256, 0, stream>>>(deg, rs, bsum);
  scan2_k<<<1, 256, 0, stream>>>(bsum, nb);
  scan3_k<<<nb, 256, 0, stream>>>(rs, bsum);
  scatter_k<<<NEDGES / 256, 256, 0, stream>>>(ei, rs, cursor, csr);

  const __half* whTs[5] = {whT1, whT2, whT3, whT3, whT3};
  const float*  bs[5]   = {b1, b2, b3, b3, b3};
  const __half* in = stateh;
  int mblocks = (NNODES + 127) / 128;   // 469
  for (int layer = 0; layer < 5; ++layer) {
    gemm_mfma_k<<<mblocks * 2, 256, 0, stream>>>(in, whTs[layer], dinv, ysh);
    gather_k<<<NNODES / 8, 256, 0, stream>>>(ysh, rs, csr, dinv, bs[layer], obufh);
    skern_k<<<NNODES / 32, 256, 0, stream>>>(obufh, l1w + layer * 256 * 32, h1acc);
    in = obufh;
  }
  skern_k<<<NNODES / 32, 256, 0, stream>>>(stateh, l1w + 1280 * 32, h1acc);
  mlp_k<<<NNODES / 8, 256, 0, stream>>>(h1acc, action, l1w + 1536 * 32, l1b, l2w, l2b, h2);
  final_k<<<NGRAPH / 4, 256, 0, stream>>>(h2, l3w, l3b, out);
}